// Round 30
// baseline (138.763 us; speedup 1.0000x reference)
//
#include <hip/hip_runtime.h>

// Locally connected layer:
// out[b,o,h,w] = sum_{c,i,j} x[b,c,h+i,w+j] * W[o,c,h,w,i,j] + bias[o,h,w]
// x: [32,32,64,64] f32, W: [64,32,62,62,3,3] f32, bias: [64,62,62] f32
// out: [32,64,62,62] f32
//
// R30 = R25's exact per-wave program, regrouped into 8-WAVE BLOCKS (512
// threads): block = (h, bhalf, o-16-tile), wave w = o-pair (o0=tile+2w).
// Rationale: 6 consecutive scheduling levers were null -> every intra-wave
// wait is pre-covered; the wall is a shared per-CU resource. Quantified
// candidate: per-CU unique x = 4 blocks x 12 KB = 48 KB > 32 KB L1, so the
// 4x inter-wave duplicate x requests thrash to L2 (~200-400 cy each).
// 8-wave blocks at 2 blocks/CU halve unique x to 24 KB (L1-resident):
// the 8x dup becomes L1 hits. Same 16 waves/CU, same per-wave FMA density,
// same FIFO invariants (gll(c)6 | x(c)12 | gll(c+1)6 -> WAITV(18)).
// Validated: wide W staging 2xGLL16+GLL4 (R25), pin-before-FENCE (R20),
// x-oldest/gll-youngest (R21), 2 o's/wave, barrier-free (R12), DPP halo
// 0x101 (R8), chunked XCD swizzle (R3), nontemporal stores, plain
// launch_bounds (min-waves clause spills: R4/R8).

#define C_  32
#define B_  32
#define O_  64
#define H_  64
#define W_  64
#define OH_ 62
#define OW_ 62

typedef float vfloat2 __attribute__((ext_vector_type(2)));
typedef float vfloat4 __attribute__((ext_vector_type(4)));

#define GLL16(gaddr, laddr)                                                     \
    __builtin_amdgcn_global_load_lds(                                           \
        (const __attribute__((address_space(1))) void*)(gaddr),                 \
        (__attribute__((address_space(3))) void*)(laddr), 16, 0, 0)

#define GLL4(gaddr, laddr)                                                      \
    __builtin_amdgcn_global_load_lds(                                           \
        (const __attribute__((address_space(1))) void*)(gaddr),                 \
        (__attribute__((address_space(3))) void*)(laddr), 4, 0, 0)

// dst[lane] = src[lane+1] within each 16-lane row (validated R8)
__device__ __forceinline__ float dpp_nextlane(float v) {
    return __int_as_float(__builtin_amdgcn_update_dpp(
        0, __float_as_int(v), 0x101, 0xf, 0xf, true));
}

#define WAITV(n) do {                                                           \
        asm volatile("s_waitcnt vmcnt(" #n ")" ::: "memory");                   \
        __builtin_amdgcn_sched_barrier(0);                                      \
    } while (0)

#define FENCE() __builtin_amdgcn_sched_barrier(0)

__global__ __launch_bounds__(512)
void lcl_kernel(const float* __restrict__ x,
                const float* __restrict__ Wt,
                const float* __restrict__ bias,
                float* __restrict__ out) {
    // W rows: [2 buffers][8 waves][2 o's][576 floats] = 73728 B -> 2 blk/CU
    // (same 16 waves/CU as R25's 4 blk x 4 waves). Slot 2304 B, 16B-aligned.
    __shared__ __attribute__((aligned(16))) float ldsW[2][8][2][576];

    // ---- chunked XCD swizzle (hw: XCD = blockIdx.x % 8); 496 = 8 * 62
    const int i0      = blockIdx.x;
    const int logical = (i0 & 7) * 62 + (i0 >> 3);
    const int bhalf   = logical & 1;                 // batches 0-15 / 16-31
    const int pair    = logical >> 1;                // 0..247
    const int ot      = pair & 3;                    // o-16-tile (fast)
    const int h       = pair >> 2;                   // 0..61

    const int wv_i = threadIdx.x >> 6;               // wave 0..7
    const int o0   = (ot << 4) + (wv_i << 1);        // this wave: o0, o0+1
    const int lane = threadIdx.x & 63;
    const int wg   = lane & 15;                      // w0 = 4*wg
    const int bg   = lane >> 4;                      // 4 batches per bg
    const int w0   = wg * 4;
    const int b0   = bhalf * 16 + bg * 4;
    const bool full = (wg < 15);                     // wg15 stores only w=60,61

    float acc0[4][4], acc1[4][4];
#pragma unroll
    for (int bi = 0; bi < 4; ++bi)
#pragma unroll
        for (int wi = 0; wi < 4; ++wi) { acc0[bi][wi] = 0.f; acc1[bi][wi] = 0.f; }

    // W row bases (floats): o*C*34596 + h*558
    const long wrow0 = (long)o0 * (C_ * 34596) + (long)h * 558;
    const long wrow1 = wrow0 + (long)C_ * 34596;     // o0+1

    // x byte base for (b0, h, w0) - identical across the block's 8 waves
    const char* xb0 = (const char*)x + (unsigned)b0 * 524288u
                      + (unsigned)h * 256u + (unsigned)wg * 16u;

    // stage one 2232-B W row: 2x dwordx4 gll + dword tail [1976,2232)
    // (overlap [1976,2048) double-written with identical data; R25-validated)
#define STAGE_ROW(srow, drow) do {                                              \
        GLL16((srow) + lane * 16, (drow));                                      \
        GLL16((srow) + 1024 + lane * 16, (drow) + 1024);                        \
        GLL4((srow) + 1976 + lane * 4, (drow) + 1976);                          \
    } while (0)

#define STAGE_W2(buf, cidx) do {                                                \
        const char* s0_ = (const char*)(Wt + wrow0 + (long)(cidx) * 34596);     \
        const char* s1_ = (const char*)(Wt + wrow1 + (long)(cidx) * 34596);     \
        char* d0_ = (char*)&ldsW[buf][wv_i][0][0];                              \
        char* d1_ = (char*)&ldsW[buf][wv_i][1][0];                              \
        STAGE_ROW(s0_, d0_);                                                    \
        STAGE_ROW(s1_, d1_);                                                    \
    } while (0)

    // lane's 36 W floats for o-slot oo_ (9 ds_read_b128; 144-B lane stride =
    // 2-way alias + 4-way bg broadcast, conflict-free per counters).
#define DSREAD_W(buf, oo_) do {                                                 \
        const char* r_ = (const char*)&ldsW[buf][wv_i][oo_][0] + wg * 144;      \
        _Pragma("unroll")                                                       \
        for (int q_ = 0; q_ < 9; ++q_)                                          \
            wq[q_] = *reinterpret_cast<const vfloat4*>(r_ + q_ * 16);           \
    } while (0)

#define WQ(t) (wq[(t) >> 2][(t) & 3])

    // issue 3 float4 rows of batch b0+bi_ for channel cidx into slot s_
#define XLD(s_, cidx, bi_) do {                                                 \
        const char* p_ = xb0 + (unsigned)(bi_) * 524288u                        \
                         + (unsigned)(cidx) * 16384u;                           \
        xv##s_[0] = *reinterpret_cast<const float4*>(p_);                       \
        xv##s_[1] = *reinterpret_cast<const float4*>(p_ + 256);                 \
        xv##s_[2] = *reinterpret_cast<const float4*>(p_ + 512);                 \
    } while (0)

    // expand slot s_ via DPP halo, 36 FMAs into ACC[bi_]
#define FMA1(ACC, s_, bi_) do {                                                 \
        float xr_[3][6];                                                        \
        _Pragma("unroll")                                                       \
        for (int r_ = 0; r_ < 3; ++r_) {                                        \
            xr_[r_][0] = xv##s_[r_].x; xr_[r_][1] = xv##s_[r_].y;               \
            xr_[r_][2] = xv##s_[r_].z; xr_[r_][3] = xv##s_[r_].w;               \
            xr_[r_][4] = dpp_nextlane(xv##s_[r_].x);                            \
            xr_[r_][5] = dpp_nextlane(xv##s_[r_].y);                            \
        }                                                                       \
        _Pragma("unroll")                                                       \
        for (int wi_ = 0; wi_ < 4; ++wi_)                                       \
        _Pragma("unroll")                                                       \
        for (int ii_ = 0; ii_ < 3; ++ii_)                                       \
        _Pragma("unroll")                                                       \
        for (int j_ = 0; j_ < 3; ++j_)                                          \
            ACC[bi_][wi_] = fmaf(xr_[ii_][wi_ + j_],                            \
                                 WQ(wi_ * 9 + ii_ * 3 + j_), ACC[bi_][wi_]);    \
    } while (0)

    vfloat4 wq[9];
    float4  xvA[3], xvB[3], xvC[3], xvD[3];

    // ---- prologue: depth-2 W prefetch, then x(0) as the oldest-next VMEM
    STAGE_W2(0, 0);
    STAGE_W2(1, 1);
    XLD(A, 0, 0);
    XLD(B, 0, 1);
    XLD(C, 0, 2);
    XLD(D, 0, 3);

    for (int c = 0; c < C_; ++c) {
        const int p = c & 1;
        // invariant: outstanding = gll(c) 6 + x(c) 12 + gll(c+1) 6 = 24.
        // vmcnt(18) retires exactly gll(c) (2 channels old -> ~free).
        WAITV(18);
        DSREAD_W(p, 0);                   // wq := o0 row
        FENCE();
        FMA1(acc0, A, 0);                 // waits x(c) only (oldest in queue)
        FMA1(acc0, B, 1);
        FMA1(acc0, C, 2);
        FMA1(acc0, D, 3);
        FENCE();
        DSREAD_W(p, 1);                   // wq := o1 row (same regs)
        FENCE();
        FMA1(acc1, A, 0);
        FMA1(acc1, B, 1);
        FMA1(acc1, C, 2);
        FMA1(acc1, D, 3);
        FENCE();
        if (c + 1 < C_) {                 // x(c+1): oldest VMEM of channel c+1
            XLD(A, c + 1, 0);
            XLD(B, c + 1, 1);
            XLD(C, c + 1, 2);
            XLD(D, c + 1, 3);
        }
        FENCE();
        {                                 // gll(c+2): YOUNGEST. Clamped dup at
            const int cn = (c + 2 < C_) ? (c + 2) : (C_ - 1);  // c=30,31 keeps
            STAGE_W2(p, cn);              // the count invariant; buf p was
        }                                 // fully ds_read above (no race).
    }

    // ---- epilogue: bias + nontemporal float2 stores (8B-aligned), 2 o's
#pragma unroll
    for (int oo = 0; oo < 2; ++oo) {
        const int oc = o0 + oo;
        const float* brow = bias + ((long)oc * OH_ + h) * OW_ + w0;
        float2 bv0 = *reinterpret_cast<const float2*>(brow);
        float2 bv1;
        if (full) bv1 = *reinterpret_cast<const float2*>(brow + 2);
        else { bv1.x = 0.f; bv1.y = 0.f; }
#pragma unroll
        for (int bi = 0; bi < 4; ++bi) {
            const float* a_ = oo ? acc1[bi] : acc0[bi];
            float* orow = out + (((long)(b0 + bi) * O_ + oc) * OH_ + h) * OW_ + w0;
            vfloat2 s0; s0.x = a_[0] + bv0.x; s0.y = a_[1] + bv0.y;
            __builtin_nontemporal_store(s0, reinterpret_cast<vfloat2*>(orow));
            if (full) {
                vfloat2 s1; s1.x = a_[2] + bv1.x; s1.y = a_[3] + bv1.y;
                __builtin_nontemporal_store(s1, reinterpret_cast<vfloat2*>(orow) + 1);
            }
        }
    }

#undef STAGE_ROW
#undef STAGE_W2
#undef DSREAD_W
#undef WQ
#undef XLD
#undef FMA1
}

extern "C" void kernel_launch(void* const* d_in, const int* in_sizes, int n_in,
                              void* d_out, int out_size, void* d_ws, size_t ws_size,
                              hipStream_t stream) {
    const float* x    = (const float*)d_in[0];
    const float* Wt   = (const float*)d_in[1];
    const float* bias = (const float*)d_in[2];
    float* out        = (float*)d_out;

    dim3 grid(496);    // (62 h x 4 o-tiles x 2 batch-halves), XCD-swizzled
    dim3 block(512);   // 8 waves sharing one 12 KB x slab per channel
    lcl_kernel<<<grid, block, 0, stream>>>(x, Wt, bias, out);
}